// Round 10
// baseline (313.364 us; speedup 1.0000x reference)
//
#include <hip/hip_runtime.h>
#include <stdint.h>

#define NBATCH 16
#define HW_ (1 << 20)            // 1024*1024 per batch
#define TPB 256

#define NBPB_H 64                // blocks per batch for hist pass
#define EPB_H (HW_ / NBPB_H)     // 16384 elements per block
#define ITER_H (EPB_H / (TPB * 4)) // 16 float4 per thread

#define NBINS 8192               // fine bins on score_bits >> 12; base 0x3F400
#define FBASE 0x3F400
#define NCOARSE 64               // coarse chunks of 128 fine bins

#define NBPB_F 256               // blocks per batch for main pass
#define FCHUNK (HW_ / NBPB_F)    // 4096 elements per block

#define CAND_CAP 32768           // ambiguous candidates per batch (fine-bin count ~500)
#define LCAP 512                 // per-block LDS candidate capacity
#define TIE_CAP 4096
#define CSTR 64                  // u32 stride between per-batch counters (256 B)

typedef float f4v __attribute__((ext_vector_type(4)));

struct BParams {
    unsigned int k;        // n_train
    unsigned int bin1f;    // selected fine bin as raw (score_bits>>12); 0xFFFFFFFF if k==0
    unsigned int r;        // rank remaining within bin1f (k - count_above)
    unsigned int mode;     // 0 = no train, 1 = normal
};

__device__ __forceinline__ unsigned int score_bits(float p, int m) {
    bool correct = (p > 0.5f) == (m == 1);
    float conf = fmaxf(p, 1.0f - p);
    float base = correct ? ((conf > 0.85f) ? 1.0f : 2.0f)
                         : ((conf > 0.85f) ? 4.0f : 3.0f);
    float bonus = (conf - 0.5f) * 0.5f;   // exact in f32
    float s = correct ? (base - bonus) : (base + bonus);
    return __float_as_uint(s);            // positive floats: bit order == value order
}

// Pass 1 fused: fine histogram (global atomics) + per-batch coarse hist; the last
// arriver per batch reads 64 coarse + 128 fine bins (~1 KB) and computes prm[b].
__global__ void k_histfind(const float4* __restrict__ pred4, const int4* __restrict__ mask4,
                           unsigned int* __restrict__ hist1, unsigned int* __restrict__ coarse,
                           unsigned int* __restrict__ doneA, BParams* __restrict__ prm) {
    __shared__ unsigned int lh[NBINS];     // 32 KB
    __shared__ unsigned int sc[NCOARSE + 1];
    __shared__ unsigned int hs[129];
    __shared__ unsigned int miscF[2];      // [0]=c* [1]=cumAbove
    __shared__ unsigned int lastFlag;
    int b = blockIdx.x / NBPB_H;
    int blk = blockIdx.x % NBPB_H;
    int t = threadIdx.x;
    for (int i = t; i < NBINS; i += TPB) lh[i] = 0;
    __syncthreads();
    int l4base = blk * (EPB_H / 4);
    for (int j = 0; j < ITER_H; j++) {
        int i4l = l4base + j * TPB + t;
        size_t g4 = (size_t)b * (HW_ / 4) + i4l;
        float4 p = pred4[g4];
        int4 m = mask4[g4];
        float pa[4] = {p.x, p.y, p.z, p.w};
        int ma[4] = {m.x, m.y, m.z, m.w};
#pragma unroll
        for (int l = 0; l < 4; l++) {
            if (ma[l] != 2) {
                unsigned int sb = score_bits(pa[l], ma[l]);
                int fb = (int)(sb >> 12) - FBASE;
                fb = min(max(fb, 0), NBINS - 1);
                atomicAdd(&lh[fb], 1u);
            }
        }
    }
    __syncthreads();
    // flush fine hist (sparse: ~1000 populated bins)
    for (int i = t; i < NBINS; i += TPB) {
        unsigned int v = lh[i];
        if (v) atomicAdd(&hist1[b * NBINS + i], v);
    }
    // coarse sums: thread t<64 sums its 128-bin chunk with diagonal access (2-way max)
    if (t < NCOARSE) {
        unsigned int s = 0;
#pragma unroll
        for (int jj = 0; jj < 128; jj++) s += lh[t * 128 + ((jj + t) & 127)];
        if (s) atomicAdd(&coarse[b * CSTR + t], s);
    }
    __syncthreads();
    if (t == 0) {
        __threadfence();   // release our atomics before signaling
        lastFlag = (atomicAdd(&doneA[b * CSTR], 1u) == NBPB_H - 1) ? 1u : 0u;
    }
    __syncthreads();
    if (!lastFlag) return;
    if (t == 0) __threadfence();   // acquire
    __syncthreads();

    // ---- finder: coarse suffix scan ----
    if (t < NCOARSE) sc[t] = coarse[b * CSTR + t];
    if (t == 0) sc[NCOARSE] = 0;
    __syncthreads();
    for (int off = 1; off < NCOARSE; off <<= 1) {
        unsigned int a = 0;
        if (t < NCOARSE) a = (t + off < NCOARSE) ? sc[t + off] : 0u;
        __syncthreads();
        if (t < NCOARSE) sc[t] += a;
        __syncthreads();
    }
    unsigned int n = sc[0];                                  // total annotated
    unsigned int k = (unsigned int)(int)((float)n * 0.5f);   // astype(f32)*0.5 -> int32
    if (k == 0) {
        if (t == 0) {
            BParams P; P.k = 0; P.bin1f = 0xFFFFFFFFu; P.r = 0; P.mode = 0;
            prm[b] = P;
        }
        return;
    }
    if (t < NCOARSE && sc[t] >= k && sc[t + 1] < k) {  // unique boundary chunk
        miscF[0] = (unsigned int)t;
        miscF[1] = sc[t + 1];                          // count above chunk
    }
    __syncthreads();
    unsigned int cstar = miscF[0];
    unsigned int rk = k - miscF[1];                    // rank from top within chunk
    // ---- fine suffix scan within chunk c* (128 bins) ----
    if (t < 128) hs[t] = hist1[(size_t)b * NBINS + cstar * 128 + t];
    if (t == 0) hs[128] = 0;
    __syncthreads();
    for (int off = 1; off < 128; off <<= 1) {
        unsigned int a = 0;
        if (t < 128) a = (t + off < 128) ? hs[t + off] : 0u;
        __syncthreads();
        if (t < 128) hs[t] += a;
        __syncthreads();
    }
    if (t < 128 && hs[t] >= rk && hs[t + 1] < rk) {
        BParams P;
        P.k = k;
        P.bin1f = (unsigned int)(FBASE + cstar * 128 + t);
        P.r = rk - hs[t + 1];
        P.mode = 1;
        prm[b] = P;
    }
}

// Main fused pass: byte-code mask staging (stride-1 LDS, no conflicts), BCE for
// definite-train, per-block LDS candidate staging, one global atomic per block.
__global__ void k_main(const float4* __restrict__ pred4, const int4* __restrict__ mask4,
                       const BParams* __restrict__ prm, float* __restrict__ out,
                       float* __restrict__ partials, unsigned int* __restrict__ cand_cnt,
                       unsigned int* __restrict__ cand_idx, unsigned int* __restrict__ cand_sb,
                       float* __restrict__ cand_bce) {
    int b = blockIdx.x / NBPB_F;
    int blk = blockIdx.x % NBPB_F;
    BParams P = prm[b];
    unsigned int target = P.bin1f;
    __shared__ unsigned int lcode[FCHUNK / 4];   // 2-bit code per elem, 4 per u32
    __shared__ float red[TPB];
    __shared__ unsigned int l_idx[LCAP];
    __shared__ unsigned int l_sb[LCAP];
    __shared__ float l_bce[LCAP];
    __shared__ unsigned int lcnt;
    __shared__ unsigned int gbase;
    if (threadIdx.x == 0) lcnt = 0;
    __syncthreads();
    float acc = 0.0f;
    int ibase = blk * FCHUNK;
    for (int j = 0; j < FCHUNK / (TPB * 4); j++) {   // 4 iterations
        int v = j * TPB + threadIdx.x;               // word index [0,1024)
        size_t g4 = (size_t)b * (HW_ / 4) + (ibase / 4) + v;
        float4 p = pred4[g4];
        int4 m = mask4[g4];
        float pa[4] = {p.x, p.y, p.z, p.w};
        int ma[4] = {m.x, m.y, m.z, m.w};
        unsigned int cw = 0;
#pragma unroll
        for (int l = 0; l < 4; l++) {
            bool ann = (ma[l] != 2);
            unsigned int sb = score_bits(pa[l], ma[l]);
            unsigned int fine = sb >> 12;
            bool tr = ann && (fine > target);
            bool amb = ann && (fine == target);
            unsigned int code = (tr ? 1u : 0u) | ((ann && !tr) ? 2u : 0u);
            cw |= code << (8 * l);
            float bce = 0.0f;
            if (tr || amb) {
                float pc = fminf(fmaxf(pa[l], 1e-7f), 1.0f - 1e-7f);
                bce = (ma[l] == 1) ? -__logf(pc) : -__logf(1.0f - pc);
            }
            if (tr) acc += bce;
            if (amb) {
                unsigned int p0 = atomicAdd(&lcnt, 1u);  // LDS atomic
                if (p0 < LCAP) {
                    l_idx[p0] = (unsigned int)(ibase + v * 4 + l);
                    l_sb[p0] = sb;
                    l_bce[p0] = bce;
                } else {
                    unsigned int gp = atomicAdd(&cand_cnt[b * CSTR], 1u);
                    if (gp < CAND_CAP) {
                        size_t o = (size_t)b * CAND_CAP + gp;
                        cand_idx[o] = (unsigned int)(ibase + v * 4 + l);
                        cand_sb[o] = sb;
                        cand_bce[o] = bce;
                    }
                }
            }
        }
        lcode[v] = cw;   // stride-1 ds_write_b32, conflict-free
    }
    __syncthreads();
    // one global reservation per block, coalesced copy of LDS candidate list
    unsigned int n = min(lcnt, (unsigned int)LCAP);
    if (threadIdx.x == 0 && n > 0)
        gbase = atomicAdd(&cand_cnt[b * CSTR], n);
    __syncthreads();
    for (unsigned int i = threadIdx.x; i < n; i += TPB) {
        unsigned int pos = gbase + i;
        if (pos < CAND_CAP) {
            size_t o = (size_t)b * CAND_CAP + pos;
            cand_idx[o] = l_idx[i];
            cand_sb[o] = l_sb[i];
            cand_bce[o] = l_bce[i];
        }
    }
    // out layout: out[0]=loss, train at out[1 .. 1+16M), holdout next.
    float* trout = out + 1;
    float* hoout = out + 1 + (size_t)NBATCH * HW_;
    size_t Gbase = (size_t)b * HW_ + (size_t)ibase;
    // aligned float4 stores covering local elems [3, 4095)
    for (int v = threadIdx.x; v < FCHUNK / 4 - 1; v += TPB) {
        unsigned int w0 = lcode[v];
        unsigned int w1 = lcode[v + 1];
        unsigned int c0 = (w0 >> 24) & 0xFFu;
        unsigned int c1 = w1 & 0xFFu;
        unsigned int c2 = (w1 >> 8) & 0xFFu;
        unsigned int c3 = (w1 >> 16) & 0xFFu;
        int e = 3 + 4 * v;
        f4v tv = { (float)(c0 & 1u), (float)(c1 & 1u), (float)(c2 & 1u), (float)(c3 & 1u) };
        f4v hv = { (float)((c0 >> 1) & 1u), (float)((c1 >> 1) & 1u),
                   (float)((c2 >> 1) & 1u), (float)((c3 >> 1) & 1u) };
        __builtin_nontemporal_store(tv, (f4v*)(trout + Gbase + e));
        __builtin_nontemporal_store(hv, (f4v*)(hoout + Gbase + e));
    }
    if (threadIdx.x < 3) {   // head elems 0,1,2
        unsigned int c = (lcode[0] >> (8 * threadIdx.x)) & 0xFFu;
        trout[Gbase + threadIdx.x] = (float)(c & 1u);
        hoout[Gbase + threadIdx.x] = (float)((c >> 1) & 1u);
    }
    if (threadIdx.x == 3) {  // tail elem 4095
        unsigned int c = (lcode[FCHUNK / 4 - 1] >> 24) & 0xFFu;
        trout[Gbase + FCHUNK - 1] = (float)(c & 1u);
        hoout[Gbase + FCHUNK - 1] = (float)((c >> 1) & 1u);
    }
    red[threadIdx.x] = acc;
    __syncthreads();
    for (int off = TPB / 2; off > 0; off >>= 1) {
        if (threadIdx.x < off) red[threadIdx.x] += red[threadIdx.x + off];
        __syncthreads();
    }
    if (threadIdx.x == 0) partials[blockIdx.x] = red[0];
}

// Fixup + loss merged: 16 blocks. Each does its batch's exact select/scatter;
// the last arriver (16 fences total, cheap) computes the final loss.
__global__ void k_fixuploss(const unsigned int* __restrict__ cand_cnt,
                            const unsigned int* __restrict__ cand_idx,
                            const unsigned int* __restrict__ cand_sb,
                            const float* __restrict__ cand_bce,
                            const BParams* __restrict__ prm, float* __restrict__ out,
                            float* __restrict__ tie_partials,
                            const float* __restrict__ partials,
                            unsigned int* __restrict__ doneC) {
    int b = blockIdx.x;
    int t = threadIdx.x;
    __shared__ unsigned int h[4096];
    __shared__ unsigned int cs_[257];
    __shared__ unsigned int tie_idx[TIE_CAP];
    __shared__ unsigned int misc[8];  // [0]=v* [1]=T [2]=allTies [3]=tieCnt [4]=idxcut
    __shared__ float red[TPB];
    __shared__ unsigned int lastFlag;
    BParams P = prm[b];
    if (P.mode != 0) {
        unsigned int C = cand_cnt[b * CSTR];
        if (C > CAND_CAP) C = CAND_CAP;
        const unsigned int* ci = cand_idx + (size_t)b * CAND_CAP;
        const unsigned int* cs = cand_sb + (size_t)b * CAND_CAP;
        const float* cb = cand_bce + (size_t)b * CAND_CAP;
        for (int i = t; i < 4096; i += TPB) h[i] = 0;
        if (t < 8) misc[t] = (t == 4) ? 0xFFFFFFFFu : 0u;
        __syncthreads();
        // exact 4096-bin hist on low-12 bits
        for (unsigned int i = t; i < C; i += TPB)
            atomicAdd(&h[cs[i] & 0xFFFu], 1u);
        __syncthreads();
        {
            unsigned int gs = 0;
#pragma unroll
            for (int j = 0; j < 16; j++) gs += h[t * 16 + j];
            cs_[t] = gs;
            if (t == 0) cs_[256] = 0;
        }
        __syncthreads();
        for (int off = 1; off < 256; off <<= 1) {
            unsigned int a = (t + off < 256) ? cs_[t + off] : 0u;
            __syncthreads();
            cs_[t] += a;
            __syncthreads();
        }
        if (cs_[t] >= P.r && cs_[t + 1] < P.r) {
            unsigned int cum = cs_[t + 1];
            for (int j = 15; j >= 0; j--) {
                unsigned int hb = h[t * 16 + j];
                if (cum + hb >= P.r) {
                    unsigned int T = P.r - cum;
                    misc[0] = (unsigned int)(t * 16 + j);
                    misc[1] = T;
                    misc[2] = (T == hb) ? 1u : 0u;
                    break;
                }
                cum += hb;
            }
        }
        __syncthreads();
        unsigned int vstar = misc[0], T = misc[1];
        bool allTies = (misc[2] != 0);
        unsigned int idxcut;
        if (allTies) {
            idxcut = 0xFFFFFFFFu;
        } else {
            for (unsigned int i = t; i < C; i += TPB) {
                if ((cs[i] & 0xFFFu) == vstar) {
                    unsigned int p = atomicAdd(&misc[3], 1u);
                    if (p < TIE_CAP) tie_idx[p] = ci[i];
                }
            }
            __syncthreads();
            unsigned int E2 = misc[3];
            if (E2 > TIE_CAP) E2 = TIE_CAP;
            for (unsigned int i = t; i < E2; i += TPB) {
                unsigned int vi = tie_idx[i];
                unsigned int cnt = 0;
                for (unsigned int j = 0; j < E2; j++) cnt += (tie_idx[j] < vi) ? 1u : 0u;
                if (cnt == T - 1) misc[4] = vi;  // T-th smallest tie index
            }
            __syncthreads();
            idxcut = misc[4];
        }
        // scatter-correct masks + tie BCE
        float acc = 0.0f;
        float* trout = out + 1;
        float* hoout = out + 1 + (size_t)NBATCH * HW_;
        size_t base = (size_t)b * HW_;
        for (unsigned int i = t; i < C; i += TPB) {
            unsigned int low = cs[i] & 0xFFFu;
            bool tr = (low > vstar) || (low == vstar && ci[i] <= idxcut);
            if (tr) {
                trout[base + ci[i]] = 1.0f;
                hoout[base + ci[i]] = 0.0f;
                acc += cb[i];
            }
        }
        red[t] = acc;
        __syncthreads();
        for (int off = TPB / 2; off > 0; off >>= 1) {
            if (t < off) red[t] += red[t + off];
            __syncthreads();
        }
        if (t == 0) tie_partials[b] = red[0];
    } else {
        if (t == 0) tie_partials[b] = 0.0f;
    }
    // ---- last arriver (of 16) computes the loss ----
    if (t == 0) {
        __threadfence();
        lastFlag = (atomicAdd(doneC, 1u) == NBATCH - 1) ? 1u : 0u;
    }
    __syncthreads();
    if (!lastFlag) return;
    {
        __shared__ double dred[TPB];
        double s = 0.0;
        for (int i = t; i < NBATCH * NBPB_F; i += TPB) s += (double)partials[i];
        if (t < NBATCH) s += (double)tie_partials[t];
        dred[t] = s;
        __syncthreads();
        for (int off = TPB / 2; off > 0; off >>= 1) {
            if (t < off) dred[t] += dred[t + off];
            __syncthreads();
        }
        if (t == 0) {
            unsigned long long den = 0;
            for (int b2 = 0; b2 < NBATCH; b2++) den += prm[b2].k;
            float denf = (float)den + 1e-7f;
            out[0] = (float)dred[0] / denf;
        }
    }
}

extern "C" void kernel_launch(void* const* d_in, const int* in_sizes, int n_in,
                              void* d_out, int out_size, void* d_ws, size_t ws_size,
                              hipStream_t stream) {
    const float4* pred4 = (const float4*)d_in[0];
    const int4* mask4 = (const int4*)d_in[1];
    float* out = (float*)d_out;

    // workspace layout (u32 words); zeroed region first:
    // hist1 | coarse(padded) | doneA(padded) | cand_cnt(padded) | doneC
    unsigned int* hist1 = (unsigned int*)d_ws;                  // 16*8192
    unsigned int* coarse = hist1 + NBATCH * NBINS;              // 16*CSTR
    unsigned int* doneA = coarse + NBATCH * CSTR;               // 16*CSTR
    unsigned int* cand_cnt = doneA + NBATCH * CSTR;             // 16*CSTR
    unsigned int* doneC = cand_cnt + NBATCH * CSTR;             // 1 (pad 64)
    BParams* prm = (BParams*)(doneC + 64);                      // 16 structs
    float* partials = (float*)(prm + NBATCH);                   // 16*256
    float* tie_partials = partials + NBATCH * NBPB_F;           // 16
    unsigned int* cand_idx = (unsigned int*)(tie_partials + NBATCH);  // 16*32768
    unsigned int* cand_sb = cand_idx + NBATCH * CAND_CAP;
    float* cand_bce = (float*)(cand_sb + NBATCH * CAND_CAP);

    size_t zero_bytes = (size_t)(NBATCH * NBINS + 3 * NBATCH * CSTR + 64) * 4;
    hipMemsetAsync(d_ws, 0, zero_bytes, stream);

    k_histfind<<<dim3(NBATCH * NBPB_H), dim3(TPB), 0, stream>>>(pred4, mask4, hist1,
                                                                coarse, doneA, prm);
    k_main<<<dim3(NBATCH * NBPB_F), dim3(TPB), 0, stream>>>(pred4, mask4, prm, out, partials,
                                                            cand_cnt, cand_idx, cand_sb, cand_bce);
    k_fixuploss<<<dim3(NBATCH), dim3(TPB), 0, stream>>>(cand_cnt, cand_idx, cand_sb, cand_bce,
                                                        prm, out, tie_partials, partials, doneC);
}